// Round 7
// baseline (46.209 us; speedup 1.0000x reference)
//
#include <hip/hip_runtime.h>

#define BB 64
#define NN 32
#define IND 128
#define HD 512
#define OD 256
#define NPERM 992

typedef __attribute__((ext_vector_type(8))) _Float16 half8;
typedef __attribute__((ext_vector_type(4))) _Float16 half4;
typedef __attribute__((ext_vector_type(16))) float f32x16;

typedef __attribute__((address_space(3))) char lds_char_t;
typedef __attribute__((address_space(1))) const char gbl_char_t;

__device__ __forceinline__ void glds16(const void* g, void* l) {
    __builtin_amdgcn_global_load_lds((gbl_char_t*)g, (lds_char_t*)l, 16, 0, 0);
}

#define WAITVM8 asm volatile("s_waitcnt vmcnt(8)" ::: "memory")
#define WAITVM4 asm volatile("s_waitcnt vmcnt(4)" ::: "memory")
#define WAITVM1 asm volatile("s_waitcnt vmcnt(1)" ::: "memory")
#define WAITLGKM asm volatile("s_waitcnt lgkmcnt(0)" ::: "memory")
#define RBAR __builtin_amdgcn_s_barrier()

__device__ __forceinline__ half8 relu8(half8 x) {
    half8 z = 0;
    return __builtin_elementwise_max(x, z);
}

// ================= prep: one kernel, 320 blocks x 512 threads (proven) =================
#define XTO 69632
__global__ __launch_bounds__(512, 4) void kprep(
    const float* __restrict__ x, const float* __restrict__ W1, const float* __restrict__ b1,
    const float* __restrict__ W2, _Float16* __restrict__ W2t,
    const float* __restrict__ b3, float* __restrict__ out,
    _Float16* __restrict__ U, _Float16* __restrict__ Vo) {
    __shared__ char smem[(256 + 32) * 272];
    const int bid = blockIdx.x;
    const int t = threadIdx.x;

    if (bid >= 256) {
        const int bid2 = bid - 256;
        float (*tile)[65] = (float (*)[65])smem;
        if (t < 256) out[(size_t)bid2 * OD + t] = (float)NPERM * b3[t];
        const int k0 = (bid2 & 7) * 64, c0 = (bid2 >> 3) * 64;
        const int cin = t & 63, r0 = (t >> 6) * 8;
#pragma unroll
        for (int rr = 0; rr < 8; ++rr)
            tile[r0 + rr][cin] = W2[(size_t)(k0 + r0 + rr) * HD + c0 + cin];
        __syncthreads();
        const int kout = t & 63;
#pragma unroll
        for (int rr = 0; rr < 8; ++rr) {
            int c = r0 + rr;
            W2t[(size_t)(c0 + c) * HD + k0 + kout] = (_Float16)tile[kout][c];
        }
        return;
    }

    const int g = bid & 3, b = bid >> 2;
    const int h0 = (g & 1) * 256;
    const int koff = (g >> 1) * 128;

    {
        const int n = t >> 4, c8 = (t & 15) * 8;
        const float* src = x + ((size_t)(b * NN + n)) * IND + c8;
        float4 f0 = *(const float4*)src;
        float4 f1 = *(const float4*)(src + 4);
        half8 h;
        h[0] = (_Float16)f0.x; h[1] = (_Float16)f0.y;
        h[2] = (_Float16)f0.z; h[3] = (_Float16)f0.w;
        h[4] = (_Float16)f1.x; h[5] = (_Float16)f1.y;
        h[6] = (_Float16)f1.z; h[7] = (_Float16)f1.w;
        *(half8*)(smem + XTO + n * 272 + c8 * 2) = h;
    }
    {
        const int ht = t & 63, ktb = t >> 6;
#pragma unroll
        for (int it = 0; it < 4; ++it) {
            const int kt = ktb + it * 8;
            const float* wsrc = W1 + (size_t)(koff + kt * 4) * HD + h0 + ht * 4;
            float4 v0 = *(const float4*)(wsrc);
            float4 v1 = *(const float4*)(wsrc + HD);
            float4 v2 = *(const float4*)(wsrc + 2 * HD);
            float4 v3 = *(const float4*)(wsrc + 3 * HD);
            char* wdst = smem + (size_t)(ht * 4) * 272 + kt * 8;
            half4 o0 = {(_Float16)v0.x, (_Float16)v1.x, (_Float16)v2.x, (_Float16)v3.x};
            half4 o1 = {(_Float16)v0.y, (_Float16)v1.y, (_Float16)v2.y, (_Float16)v3.y};
            half4 o2 = {(_Float16)v0.z, (_Float16)v1.z, (_Float16)v2.z, (_Float16)v3.z};
            half4 o3 = {(_Float16)v0.w, (_Float16)v1.w, (_Float16)v2.w, (_Float16)v3.w};
            *(half4*)(wdst) = o0;
            *(half4*)(wdst + 272) = o1;
            *(half4*)(wdst + 544) = o2;
            *(half4*)(wdst + 816) = o3;
        }
    }
    __syncthreads();

    const int lane = t & 63, wv = t >> 6;
    const int l31 = lane & 31, hi = lane >> 5;
    const char* abase = smem + XTO + (size_t)l31 * 272 + hi * 16;
    const char* bbase = smem + (size_t)(wv * 32 + l31) * 272 + hi * 16;

    f32x16 acc;
#pragma unroll
    for (int r = 0; r < 16; ++r) acc[r] = 0.f;
#pragma unroll
    for (int ks = 0; ks < 8; ++ks) {
        half8 a  = *(const half8*)(abase + ks * 32);
        half8 bf = *(const half8*)(bbase + ks * 32);
        acc = __builtin_amdgcn_mfma_f32_32x32x16_f16(a, bf, acc, 0, 0, 0);
    }
    const int hglob = h0 + wv * 32 + l31;
    const float bias = (g < 2) ? b1[hglob] : 0.f;
    _Float16* dst = ((g < 2) ? U : Vo) + (size_t)b * NN * HD + hglob;
#pragma unroll
    for (int r = 0; r < 16; ++r) {
        int row = (r & 3) + 8 * (r >> 2) + 4 * hi;
        dst[(size_t)row * HD] = (_Float16)(acc[r] + bias);
    }
}

// ================= main k2: r6 skeleton + wave-staggered k-rotation, compact code =========
// 256 blocks (32 bp x 8 cb), one round, b-paired, counted-vmcnt gating as r6.
// Waves 0-3 iterate k 0..15; waves 4-7 iterate 8..15,0..7 (SIMD s hosts waves s, s+4 ->
// the pair is offset half a tile: one wave's MFMA burst covers the other's relu/ds phase).
// Inner loop unroll-4 (not flattened): kernel code ~4x smaller -> fits I-cache. No setprio.
#define SLOT0 65536
#define SLOT1 98304
__global__ __launch_bounds__(512, 2) void k2(
    const _Float16* __restrict__ Ug, const _Float16* __restrict__ Vg,
    const _Float16* __restrict__ W2t, const float* __restrict__ b2,
    const float* __restrict__ W3, float* __restrict__ out) {
    __shared__ char smb[131072];   // B 2x32KB | slot0 32KB (V16+U16) | slot1 32KB
    __shared__ float red[8][64];
    __shared__ float hred[64];

    const int bp = blockIdx.x;
    const int cb0 = blockIdx.y * 64;
    const int t = threadIdx.x;
    const int lane = t & 63, wid = t >> 6;
    const int l31 = lane & 31, hi = lane >> 5;
    const int lh = lane >> 5, lm = lane & 31;
    const unsigned sw = (unsigned)((l31 & 15) << 4);
    const int kst = (wid >> 2) * 8;   // stagger: waves 4-7 start half a tile in

    auto issueB = [&](int kh) {
#pragma unroll
        for (int ii = 0; ii < 4; ++ii) {
            int r = wid * 8 + ii * 2 + lh;
            const char* src = (const char*)W2t + (size_t)(cb0 + r) * 1024 + kh * 512
                              + ((lm * 16) ^ ((r & 15) << 4));
            glds16(src, smb + kh * 32768 + (wid * 8 + ii * 2) * 512);
        }
    };
    auto issueUV = [&](int bb, int kh, unsigned slotOff) {
#pragma unroll
        for (int ii = 0; ii < 2; ++ii) {       // V rows (swizzled source)
            int r = wid * 4 + ii * 2 + lh;
            const char* src = (const char*)Vg + (size_t)(bb * NN + r) * 1024 + kh * 512
                              + ((lm * 16) ^ ((r & 15) << 4));
            glds16(src, smb + slotOff + (wid * 4 + ii * 2) * 512);
        }
#pragma unroll
        for (int ii = 0; ii < 2; ++ii) {       // U rows (linear)
            int r = wid * 4 + ii * 2 + lh;
            const char* src = (const char*)Ug + (size_t)(bb * NN + r) * 1024 + kh * 512 + lm * 16;
            glds16(src, smb + slotOff + 16384 + (wid * 4 + ii * 2) * 512);
        }
    };

    // ---- prologue: B-h0, UV(b0,h0), B-h1, UV(b0,h1) = 16 glds/wave ----
    const int bA = bp * 2, bB = bp * 2 + 1;
    issueB(0);
    issueUV(bA, 0, SLOT0);
    issueB(1);
    issueUV(bA, 1, SLOT1);
    WAITVM8;   // B-h0 + slot0 landed
    RBAR;

    f32x16 acc[4][2];
    auto resetAcc = [&]() {
#pragma unroll
        for (int rf = 0; rf < 4; ++rf)
#pragma unroll
            for (int cf = 0; cf < 2; ++cf)
#pragma unroll
                for (int r = 0; r < 16; ++r) acc[rf][cf][r] = 0.f;
    };

    auto compute = [&](unsigned slotOff, int kh) {
        const unsigned ub = slotOff + 16384u + (unsigned)(wid * 4 * 512) + (unsigned)(hi * 16);
        const unsigned vb = slotOff + (unsigned)(l31 * 512);
        const unsigned bb0 = (unsigned)(kh * 32768 + l31 * 512);
        const unsigned bb1 = (unsigned)(kh * 32768 + (32 + l31) * 512);

        half8 pU0, pU1, pU2, pU3, pV, pB0, pB1;
        {
            int k0 = kst;
            unsigned ku = (unsigned)(k0 * 32);
            unsigned kx = (unsigned)(k0 * 32 + hi * 16) ^ sw;
            pU0 = *(const half8*)(smb + ub + 0 * 512 + ku);
            pU1 = *(const half8*)(smb + ub + 1 * 512 + ku);
            pU2 = *(const half8*)(smb + ub + 2 * 512 + ku);
            pU3 = *(const half8*)(smb + ub + 3 * 512 + ku);
            pV  = *(const half8*)(smb + vb + kx);
            pB0 = *(const half8*)(smb + bb0 + kx);
            pB1 = *(const half8*)(smb + bb1 + kx);
        }
#pragma unroll 4
        for (int kk = 0; kk < 16; ++kk) {
            half8 cU0 = pU0, cU1 = pU1, cU2 = pU2, cU3 = pU3;
            half8 cV = pV, cB0 = pB0, cB1 = pB1;
            if (kk < 15) {
                int kn = (kk + 1 + kst) & 15;
                unsigned ku = (unsigned)(kn * 32);
                unsigned kx = (unsigned)(kn * 32 + hi * 16) ^ sw;
                pU0 = *(const half8*)(smb + ub + 0 * 512 + ku);
                pU1 = *(const half8*)(smb + ub + 1 * 512 + ku);
                pU2 = *(const half8*)(smb + ub + 2 * 512 + ku);
                pU3 = *(const half8*)(smb + ub + 3 * 512 + ku);
                pV  = *(const half8*)(smb + vb + kx);
                pB0 = *(const half8*)(smb + bb0 + kx);
                pB1 = *(const half8*)(smb + bb1 + kx);
            }

            half8 af0 = relu8(cU0 + cV);
            half8 af1 = relu8(cU1 + cV);
            half8 af2 = relu8(cU2 + cV);
            half8 af3 = relu8(cU3 + cV);

            acc[0][0] = __builtin_amdgcn_mfma_f32_32x32x16_f16(af0, cB0, acc[0][0], 0, 0, 0);
            acc[0][1] = __builtin_amdgcn_mfma_f32_32x32x16_f16(af0, cB1, acc[0][1], 0, 0, 0);
            acc[1][0] = __builtin_amdgcn_mfma_f32_32x32x16_f16(af1, cB0, acc[1][0], 0, 0, 0);
            acc[1][1] = __builtin_amdgcn_mfma_f32_32x32x16_f16(af1, cB1, acc[1][1], 0, 0, 0);
            acc[2][0] = __builtin_amdgcn_mfma_f32_32x32x16_f16(af2, cB0, acc[2][0], 0, 0, 0);
            acc[2][1] = __builtin_amdgcn_mfma_f32_32x32x16_f16(af2, cB1, acc[2][1], 0, 0, 0);
            acc[3][0] = __builtin_amdgcn_mfma_f32_32x32x16_f16(af3, cB0, acc[3][0], 0, 0, 0);
            acc[3][1] = __builtin_amdgcn_mfma_f32_32x32x16_f16(af3, cB1, acc[3][1], 0, 0, 0);
        }
    };

    auto sums_gemv = [&]() -> float {
        float scf[2];
#pragma unroll
        for (int cf = 0; cf < 2; ++cf) {
            int col = cb0 + cf * 32 + l31;
            float b2v = b2[col];
            float s = 0.f;
#pragma unroll
            for (int rf = 0; rf < 4; ++rf) {
                int i_idx = wid * 4 + rf;
#pragma unroll
                for (int r = 0; r < 16; ++r) {
                    int row = (r & 3) + 8 * (r >> 2) + 4 * hi;  // j index
                    float h2 = fmaxf(acc[rf][cf][r] + b2v, 0.f);
                    if (row != i_idx) s += h2;
                }
            }
            s += __shfl_xor(s, 32);
            scf[cf] = s;
        }
        if (lane < 32) {
            red[wid][l31] = scf[0];
            red[wid][32 + l31] = scf[1];
        }
        WAITLGKM; RBAR;
        if (t < 64) {
            float hsum = 0.f;
#pragma unroll
            for (int w = 0; w < 8; ++w) hsum += red[w][t];
            hred[t] = hsum;
        }
        WAITLGKM; RBAR;
        int o = t & 255, gg = t >> 8;
        const float* w3p = W3 + ((size_t)(cb0 + gg * 32)) * OD + o;
        float a = 0.f;
#pragma unroll 8
        for (int j = 0; j < 32; ++j)
            a += hred[gg * 32 + j] * w3p[(size_t)j * OD];
        return a;
    };

    // ---- b0 ----
    resetAcc();
    compute(SLOT0, 0);
    RBAR;                        // all waves done reading slot0
    issueUV(bB, 0, SLOT0);       // b1 kh0 -> slot0 (fire-and-forget)
    WAITVM4;                     // B-h1 + slot1 landed (S0' outstanding)
    RBAR;
    compute(SLOT1, 1);
    RBAR;                        // all waves done reading slot1
    issueUV(bB, 1, SLOT1);       // b1 kh1 -> slot1 (fire-and-forget)
    float a0 = sums_gemv();      // lgkm-only barriers; S0'/S1' stay in flight
    WAITVM4;                     // S0' landed
    atomicAdd(&out[(size_t)bA * OD + (t & 255)], a0);
    RBAR;                        // all waves' S0' landed; hred reads done
    // ---- b1 ----
    resetAcc();
    compute(SLOT0, 0);
    WAITVM1;                     // S1' landed (b0 atomic may be outstanding)
    RBAR;
    compute(SLOT1, 1);
    float a1 = sums_gemv();
    atomicAdd(&out[(size_t)bB * OD + (t & 255)], a1);
}

extern "C" void kernel_launch(void* const* d_in, const int* in_sizes, int n_in,
                              void* d_out, int out_size, void* d_ws, size_t ws_size,
                              hipStream_t stream) {
    const float* x  = (const float*)d_in[0];
    const float* W1 = (const float*)d_in[1];
    const float* b1 = (const float*)d_in[2];
    const float* W2 = (const float*)d_in[3];
    const float* b2 = (const float*)d_in[4];
    const float* W3 = (const float*)d_in[5];
    const float* b3 = (const float*)d_in[6];
    float* out = (float*)d_out;

    _Float16* U   = (_Float16*)d_ws;                    // 2MB
    _Float16* V   = U + (size_t)BB * NN * HD;           // 2MB
    _Float16* W2t = V + (size_t)BB * NN * HD;           // 512KB

    hipLaunchKernelGGL(kprep, dim3(320), dim3(512), 0, stream,
                       x, W1, b1, W2, W2t, b3, out, U, V);
    hipLaunchKernelGGL(k2, dim3(32, 8), dim3(512), 0, stream, U, V, W2t, b2, W3, out);
}

// Round 8
// 41.962 us; speedup vs baseline: 1.1012x; 1.1012x over previous
//
#include <hip/hip_runtime.h>

#define BB 64
#define NN 32
#define IND 128
#define HD 512
#define OD 256
#define NPERM 992

typedef __attribute__((ext_vector_type(8))) _Float16 half8;
typedef __attribute__((ext_vector_type(4))) _Float16 half4;
typedef __attribute__((ext_vector_type(16))) float f32x16;

typedef __attribute__((address_space(3))) char lds_char_t;
typedef __attribute__((address_space(1))) const char gbl_char_t;

__device__ __forceinline__ void glds16(const void* g, void* l) {
    __builtin_amdgcn_global_load_lds((gbl_char_t*)g, (lds_char_t*)l, 16, 0, 0);
}

#define WAITVM8 asm volatile("s_waitcnt vmcnt(8)" ::: "memory")
#define WAITVM4 asm volatile("s_waitcnt vmcnt(4)" ::: "memory")
#define WAITVM1 asm volatile("s_waitcnt vmcnt(1)" ::: "memory")
#define WAITLGKM asm volatile("s_waitcnt lgkmcnt(0)" ::: "memory")
#define RBAR __builtin_amdgcn_s_barrier()

__device__ __forceinline__ half8 relu8(half8 x) {
    half8 z = 0;
    return __builtin_elementwise_max(x, z);
}

// ================= prep: one kernel, 320 blocks x 512 threads (proven) =================
#define XTO 69632
__global__ __launch_bounds__(512, 4) void kprep(
    const float* __restrict__ x, const float* __restrict__ W1, const float* __restrict__ b1,
    const float* __restrict__ W2, _Float16* __restrict__ W2t,
    const float* __restrict__ b3, float* __restrict__ out,
    _Float16* __restrict__ U, _Float16* __restrict__ Vo) {
    __shared__ char smem[(256 + 32) * 272];
    const int bid = blockIdx.x;
    const int t = threadIdx.x;

    if (bid >= 256) {
        const int bid2 = bid - 256;
        float (*tile)[65] = (float (*)[65])smem;
        if (t < 256) out[(size_t)bid2 * OD + t] = (float)NPERM * b3[t];
        const int k0 = (bid2 & 7) * 64, c0 = (bid2 >> 3) * 64;
        const int cin = t & 63, r0 = (t >> 6) * 8;
#pragma unroll
        for (int rr = 0; rr < 8; ++rr)
            tile[r0 + rr][cin] = W2[(size_t)(k0 + r0 + rr) * HD + c0 + cin];
        __syncthreads();
        const int kout = t & 63;
#pragma unroll
        for (int rr = 0; rr < 8; ++rr) {
            int c = r0 + rr;
            W2t[(size_t)(c0 + c) * HD + k0 + kout] = (_Float16)tile[kout][c];
        }
        return;
    }

    const int g = bid & 3, b = bid >> 2;
    const int h0 = (g & 1) * 256;
    const int koff = (g >> 1) * 128;

    {
        const int n = t >> 4, c8 = (t & 15) * 8;
        const float* src = x + ((size_t)(b * NN + n)) * IND + c8;
        float4 f0 = *(const float4*)src;
        float4 f1 = *(const float4*)(src + 4);
        half8 h;
        h[0] = (_Float16)f0.x; h[1] = (_Float16)f0.y;
        h[2] = (_Float16)f0.z; h[3] = (_Float16)f0.w;
        h[4] = (_Float16)f1.x; h[5] = (_Float16)f1.y;
        h[6] = (_Float16)f1.z; h[7] = (_Float16)f1.w;
        *(half8*)(smem + XTO + n * 272 + c8 * 2) = h;
    }
    {
        const int ht = t & 63, ktb = t >> 6;
#pragma unroll
        for (int it = 0; it < 4; ++it) {
            const int kt = ktb + it * 8;
            const float* wsrc = W1 + (size_t)(koff + kt * 4) * HD + h0 + ht * 4;
            float4 v0 = *(const float4*)(wsrc);
            float4 v1 = *(const float4*)(wsrc + HD);
            float4 v2 = *(const float4*)(wsrc + 2 * HD);
            float4 v3 = *(const float4*)(wsrc + 3 * HD);
            char* wdst = smem + (size_t)(ht * 4) * 272 + kt * 8;
            half4 o0 = {(_Float16)v0.x, (_Float16)v1.x, (_Float16)v2.x, (_Float16)v3.x};
            half4 o1 = {(_Float16)v0.y, (_Float16)v1.y, (_Float16)v2.y, (_Float16)v3.y};
            half4 o2 = {(_Float16)v0.z, (_Float16)v1.z, (_Float16)v2.z, (_Float16)v3.z};
            half4 o3 = {(_Float16)v0.w, (_Float16)v1.w, (_Float16)v2.w, (_Float16)v3.w};
            *(half4*)(wdst) = o0;
            *(half4*)(wdst + 272) = o1;
            *(half4*)(wdst + 544) = o2;
            *(half4*)(wdst + 816) = o3;
        }
    }
    __syncthreads();

    const int lane = t & 63, wv = t >> 6;
    const int l31 = lane & 31, hi = lane >> 5;
    const char* abase = smem + XTO + (size_t)l31 * 272 + hi * 16;
    const char* bbase = smem + (size_t)(wv * 32 + l31) * 272 + hi * 16;

    f32x16 acc;
#pragma unroll
    for (int r = 0; r < 16; ++r) acc[r] = 0.f;
#pragma unroll
    for (int ks = 0; ks < 8; ++ks) {
        half8 a  = *(const half8*)(abase + ks * 32);
        half8 bf = *(const half8*)(bbase + ks * 32);
        acc = __builtin_amdgcn_mfma_f32_32x32x16_f16(a, bf, acc, 0, 0, 0);
    }
    const int hglob = h0 + wv * 32 + l31;
    const float bias = (g < 2) ? b1[hglob] : 0.f;
    _Float16* dst = ((g < 2) ? U : Vo) + (size_t)b * NN * HD + hglob;
#pragma unroll
    for (int r = 0; r < 16; ++r) {
        int row = (r & 3) + 8 * (r >> 2) + 4 * hi;
        dst[(size_t)row * HD] = (_Float16)(acc[r] + bias);
    }
}

// ================= main k2: r6 skeleton + VALU/MFMA interleave (CK-v3 style) =================
// 256 blocks (32 bp x 8 cb), one round, b-paired, counted-vmcnt gating (r6, verified best).
// compute(): full unroll, depth-1 explicit prefetch (compiler deepens it), per iter the
// source order is {af-build(8 VALU); 2 MFMA} x4 pinned by sched_group_barrier so each
// wave's relu VALU issues inside its own MFMA pipe-stall slots. DS reads left unpinned.
#define SLOT0 65536
#define SLOT1 98304
__global__ __launch_bounds__(512, 2) void k2(
    const _Float16* __restrict__ Ug, const _Float16* __restrict__ Vg,
    const _Float16* __restrict__ W2t, const float* __restrict__ b2,
    const float* __restrict__ W3, float* __restrict__ out) {
    __shared__ char smb[131072];   // B 2x32KB | slot0 32KB (V16+U16) | slot1 32KB
    __shared__ float red[8][64];
    __shared__ float hred[64];

    const int bp = blockIdx.x;
    const int cb0 = blockIdx.y * 64;
    const int t = threadIdx.x;
    const int lane = t & 63, wid = t >> 6;
    const int l31 = lane & 31, hi = lane >> 5;
    const int lh = lane >> 5, lm = lane & 31;
    const unsigned sw = (unsigned)((l31 & 15) << 4);

    auto issueB = [&](int kh) {
#pragma unroll
        for (int ii = 0; ii < 4; ++ii) {
            int r = wid * 8 + ii * 2 + lh;
            const char* src = (const char*)W2t + (size_t)(cb0 + r) * 1024 + kh * 512
                              + ((lm * 16) ^ ((r & 15) << 4));
            glds16(src, smb + kh * 32768 + (wid * 8 + ii * 2) * 512);
        }
    };
    auto issueUV = [&](int bb, int kh, unsigned slotOff) {
#pragma unroll
        for (int ii = 0; ii < 2; ++ii) {       // V rows (swizzled source)
            int r = wid * 4 + ii * 2 + lh;
            const char* src = (const char*)Vg + (size_t)(bb * NN + r) * 1024 + kh * 512
                              + ((lm * 16) ^ ((r & 15) << 4));
            glds16(src, smb + slotOff + (wid * 4 + ii * 2) * 512);
        }
#pragma unroll
        for (int ii = 0; ii < 2; ++ii) {       // U rows (linear)
            int r = wid * 4 + ii * 2 + lh;
            const char* src = (const char*)Ug + (size_t)(bb * NN + r) * 1024 + kh * 512 + lm * 16;
            glds16(src, smb + slotOff + 16384 + (wid * 4 + ii * 2) * 512);
        }
    };

    // ---- prologue: B-h0, UV(b0,h0), B-h1, UV(b0,h1) = 16 glds/wave ----
    const int bA = bp * 2, bB = bp * 2 + 1;
    issueB(0);
    issueUV(bA, 0, SLOT0);
    issueB(1);
    issueUV(bA, 1, SLOT1);
    WAITVM8;   // B-h0 + slot0 landed
    RBAR;

    f32x16 acc[4][2];
    auto resetAcc = [&]() {
#pragma unroll
        for (int rf = 0; rf < 4; ++rf)
#pragma unroll
            for (int cf = 0; cf < 2; ++cf)
#pragma unroll
                for (int r = 0; r < 16; ++r) acc[rf][cf][r] = 0.f;
    };

    auto compute = [&](unsigned slotOff, int kh) {
        const unsigned ub = slotOff + 16384u + (unsigned)(wid * 4 * 512) + (unsigned)(hi * 16);
        const unsigned vb = slotOff + (unsigned)(l31 * 512);
        const unsigned bb0 = (unsigned)(kh * 32768 + l31 * 512);
        const unsigned bb1 = (unsigned)(kh * 32768 + (32 + l31) * 512);

        half8 pU0, pU1, pU2, pU3, pV, pB0, pB1;
        {
            unsigned kx = ((unsigned)(hi * 16)) ^ sw;
            pU0 = *(const half8*)(smb + ub + 0 * 512);
            pU1 = *(const half8*)(smb + ub + 1 * 512);
            pU2 = *(const half8*)(smb + ub + 2 * 512);
            pU3 = *(const half8*)(smb + ub + 3 * 512);
            pV  = *(const half8*)(smb + vb + kx);
            pB0 = *(const half8*)(smb + bb0 + kx);
            pB1 = *(const half8*)(smb + bb1 + kx);
        }
#pragma unroll
        for (int kk = 0; kk < 16; ++kk) {
            half8 cU0 = pU0, cU1 = pU1, cU2 = pU2, cU3 = pU3;
            half8 cV = pV, cB0 = pB0, cB1 = pB1;
            if (kk < 15) {
                int kn = kk + 1;
                unsigned kx = ((unsigned)(kn * 32 + hi * 16)) ^ sw;
                pU0 = *(const half8*)(smb + ub + 0 * 512 + kn * 32);
                pU1 = *(const half8*)(smb + ub + 1 * 512 + kn * 32);
                pU2 = *(const half8*)(smb + ub + 2 * 512 + kn * 32);
                pU3 = *(const half8*)(smb + ub + 3 * 512 + kn * 32);
                pV  = *(const half8*)(smb + vb + kx);
                pB0 = *(const half8*)(smb + bb0 + kx);
                pB1 = *(const half8*)(smb + bb1 + kx);
            }

            __builtin_amdgcn_s_setprio(1);
            half8 af0 = relu8(cU0 + cV);
            acc[0][0] = __builtin_amdgcn_mfma_f32_32x32x16_f16(af0, cB0, acc[0][0], 0, 0, 0);
            acc[0][1] = __builtin_amdgcn_mfma_f32_32x32x16_f16(af0, cB1, acc[0][1], 0, 0, 0);
            half8 af1 = relu8(cU1 + cV);
            acc[1][0] = __builtin_amdgcn_mfma_f32_32x32x16_f16(af1, cB0, acc[1][0], 0, 0, 0);
            acc[1][1] = __builtin_amdgcn_mfma_f32_32x32x16_f16(af1, cB1, acc[1][1], 0, 0, 0);
            half8 af2 = relu8(cU2 + cV);
            acc[2][0] = __builtin_amdgcn_mfma_f32_32x32x16_f16(af2, cB0, acc[2][0], 0, 0, 0);
            acc[2][1] = __builtin_amdgcn_mfma_f32_32x32x16_f16(af2, cB1, acc[2][1], 0, 0, 0);
            half8 af3 = relu8(cU3 + cV);
            acc[3][0] = __builtin_amdgcn_mfma_f32_32x32x16_f16(af3, cB0, acc[3][0], 0, 0, 0);
            acc[3][1] = __builtin_amdgcn_mfma_f32_32x32x16_f16(af3, cB1, acc[3][1], 0, 0, 0);
            __builtin_amdgcn_s_setprio(0);

            // pin the interleave: 4 x {8 VALU (af-build), 2 MFMA}; DS reads unpinned
#pragma unroll
            for (int gq = 0; gq < 4; ++gq) {
                __builtin_amdgcn_sched_group_barrier(0x002, 8, 0);  // VALU
                __builtin_amdgcn_sched_group_barrier(0x008, 2, 0);  // MFMA
            }
        }
    };

    auto sums_gemv = [&]() -> float {
        float scf[2];
#pragma unroll
        for (int cf = 0; cf < 2; ++cf) {
            int col = cb0 + cf * 32 + l31;
            float b2v = b2[col];
            float s = 0.f;
#pragma unroll
            for (int rf = 0; rf < 4; ++rf) {
                int i_idx = wid * 4 + rf;
#pragma unroll
                for (int r = 0; r < 16; ++r) {
                    int row = (r & 3) + 8 * (r >> 2) + 4 * hi;  // j index
                    float h2 = fmaxf(acc[rf][cf][r] + b2v, 0.f);
                    if (row != i_idx) s += h2;
                }
            }
            s += __shfl_xor(s, 32);
            scf[cf] = s;
        }
        if (lane < 32) {
            red[wid][l31] = scf[0];
            red[wid][32 + l31] = scf[1];
        }
        WAITLGKM; RBAR;
        if (t < 64) {
            float hsum = 0.f;
#pragma unroll
            for (int w = 0; w < 8; ++w) hsum += red[w][t];
            hred[t] = hsum;
        }
        WAITLGKM; RBAR;
        int o = t & 255, gg = t >> 8;
        const float* w3p = W3 + ((size_t)(cb0 + gg * 32)) * OD + o;
        float a = 0.f;
#pragma unroll 8
        for (int j = 0; j < 32; ++j)
            a += hred[gg * 32 + j] * w3p[(size_t)j * OD];
        return a;
    };

    // ---- b0 ----
    resetAcc();
    compute(SLOT0, 0);
    RBAR;                        // all waves done reading slot0
    issueUV(bB, 0, SLOT0);       // b1 kh0 -> slot0 (fire-and-forget)
    WAITVM4;                     // B-h1 + slot1 landed (S0' outstanding)
    RBAR;
    compute(SLOT1, 1);
    RBAR;                        // all waves done reading slot1
    issueUV(bB, 1, SLOT1);       // b1 kh1 -> slot1 (fire-and-forget)
    float a0 = sums_gemv();      // lgkm-only barriers; S0'/S1' stay in flight
    WAITVM4;                     // S0' landed
    atomicAdd(&out[(size_t)bA * OD + (t & 255)], a0);
    RBAR;                        // all waves' S0' landed; hred reads done
    // ---- b1 ----
    resetAcc();
    compute(SLOT0, 0);
    WAITVM1;                     // S1' landed (b0 atomic may be outstanding)
    RBAR;
    compute(SLOT1, 1);
    float a1 = sums_gemv();
    atomicAdd(&out[(size_t)bB * OD + (t & 255)], a1);
}

extern "C" void kernel_launch(void* const* d_in, const int* in_sizes, int n_in,
                              void* d_out, int out_size, void* d_ws, size_t ws_size,
                              hipStream_t stream) {
    const float* x  = (const float*)d_in[0];
    const float* W1 = (const float*)d_in[1];
    const float* b1 = (const float*)d_in[2];
    const float* W2 = (const float*)d_in[3];
    const float* b2 = (const float*)d_in[4];
    const float* W3 = (const float*)d_in[5];
    const float* b3 = (const float*)d_in[6];
    float* out = (float*)d_out;

    _Float16* U   = (_Float16*)d_ws;                    // 2MB
    _Float16* V   = U + (size_t)BB * NN * HD;           // 2MB
    _Float16* W2t = V + (size_t)BB * NN * HD;           // 512KB

    hipLaunchKernelGGL(kprep, dim3(320), dim3(512), 0, stream,
                       x, W1, b1, W2, W2t, b3, out, U, V);
    hipLaunchKernelGGL(k2, dim3(32, 8), dim3(512), 0, stream, U, V, W2t, b2, W3, out);
}